// Round 1
// baseline (274.876 us; speedup 1.0000x reference)
//
#include <hip/hip_runtime.h>
#include <hip/hip_bf16.h>
#include <stdint.h>

#define B_ 4
#define S_ 2048
#define E_ 1024

typedef __bf16 bf16;
typedef __attribute__((ext_vector_type(8))) __bf16 bf16x8;
typedef __attribute__((ext_vector_type(4))) float f32x4;
typedef __attribute__((ext_vector_type(4))) float float4v;
typedef __attribute__((ext_vector_type(4))) unsigned int uint4v;
typedef __attribute__((ext_vector_type(4))) unsigned short ushort4v;

__device__ inline unsigned short f2bf(float f) {
  union { float f; unsigned int u; } c; c.f = f;
  unsigned int u = c.u;
  unsigned int r = (u + 0x7FFFu + ((u >> 16) & 1u)) >> 16;
  return (unsigned short)r;
}

__device__ inline void load16_to_lds(const void* g, void* l) {
  __builtin_amdgcn_global_load_lds(
      (const __attribute__((address_space(1))) void*)g,
      (__attribute__((address_space(3))) void*)l,
      16, 0, 0);
}

// ---------------------------------------------------------------------------
// Merged fp32->bf16 converter: x (8192 blocks) + 3 weights (1024 each).
// ---------------------------------------------------------------------------
__global__ __launch_bounds__(256) void cvt_all(
    const float* __restrict__ x, const float* __restrict__ w0,
    const float* __restrict__ w1, const float* __restrict__ w2,
    unsigned short* __restrict__ out) {
  const long off = (long)blockIdx.x * 256 + threadIdx.x;  // float4 units
  const float* in;
  long ibase;
  if (blockIdx.x < 8192)       { in = x;  ibase = 0; }
  else if (blockIdx.x < 9216)  { in = w0; ibase = 8192L * 256; }
  else if (blockIdx.x < 10240) { in = w1; ibase = 9216L * 256; }
  else                         { in = w2; ibase = 10240L * 256; }
  float4v f = ((const float4v*)in)[off - ibase];
  ushort4v o;
  o.x = f2bf(f.x); o.y = f2bf(f.y); o.z = f2bf(f.z); o.w = f2bf(f.w);
  ((ushort4v*)out)[off] = o;
}

// ---------------------------------------------------------------------------
// gemm8: 256x256 tile, BK=64, 8 waves (2M x 4N), 8-phase pipelined schedule.
//   T2: LDS XOR-swizzle (linear gload_lds dest + pre-swizzled global source
//       + swizzled ds_read; involution byte ^= ((byte>>7)&7)<<4 per 16KB kh
//       region) -> conflict-free ds_read_b128.
//   T3/T4: 4 phases per K-tile, one half-tile (A/B x k-half) staged per
//       phase, counted s_waitcnt vmcnt(8) twice per tile (12 -> 8 in flight,
//       issue-to-need distance ~6 phases > HBM latency). Raw s_barrier (no
//       vmcnt(0) drain).
//   T5: s_setprio(1) around each 16-MFMA cluster.
// C[m][n] = sum_k A[m][k] * B[n][k]; per-wave output 128x64 (8x4 frags).
// MODE 6: fused QKV epilogue (bias + QK rows + transposed V)
// MODE 7: exp-scores + atomic fp32 row sums
// MODE 8: PV with rowsum divide (not dispatched this round)
// ---------------------------------------------------------------------------

#define MFMA_(a, b, c) __builtin_amdgcn_mfma_f32_16x16x32_bf16(a, b, c, 0, 0, 0)

#define STAGE_A8(kh, buf, kofs)                                         \
  { char* d_ = smem + (buf) * 65536 + (kh) * 16384 + wj;                \
    load16_to_lds(pA0 + (kofs) + (kh) * 32, d_);                        \
    load16_to_lds(pA1 + (kofs) + (kh) * 32, d_ + 1024); }

#define STAGE_B8(kh, buf, kofs)                                         \
  { char* d_ = smem + (buf) * 65536 + 32768 + (kh) * 16384 + wj;        \
    load16_to_lds(pB0 + (kofs) + (kh) * 32, d_);                        \
    load16_to_lds(pB1 + (kofs) + (kh) * 32, d_ + 1024); }

#define PH_READS(mh, kh)                                                \
    const char* rb_ = smem + cur * 65536 + (kh) * 16384;                \
    bf16x8 a0_ = *(const bf16x8*)(rb_ + offA[(mh) * 4 + 0]);            \
    bf16x8 a1_ = *(const bf16x8*)(rb_ + offA[(mh) * 4 + 1]);            \
    bf16x8 a2_ = *(const bf16x8*)(rb_ + offA[(mh) * 4 + 2]);            \
    bf16x8 a3_ = *(const bf16x8*)(rb_ + offA[(mh) * 4 + 3]);            \
    bf16x8 b0_ = *(const bf16x8*)(rb_ + offB[0]);                       \
    bf16x8 b1_ = *(const bf16x8*)(rb_ + offB[1]);                       \
    bf16x8 b2_ = *(const bf16x8*)(rb_ + offB[2]);                       \
    bf16x8 b3_ = *(const bf16x8*)(rb_ + offB[3])

#define PH_TAIL(mh)                                                     \
    __builtin_amdgcn_s_barrier();                                       \
    asm volatile("s_waitcnt lgkmcnt(0)" ::: "memory");                  \
    __builtin_amdgcn_s_setprio(1);                                      \
    acc[(mh)*4+0][0] = MFMA_(a0_, b0_, acc[(mh)*4+0][0]);               \
    acc[(mh)*4+0][1] = MFMA_(a0_, b1_, acc[(mh)*4+0][1]);               \
    acc[(mh)*4+0][2] = MFMA_(a0_, b2_, acc[(mh)*4+0][2]);               \
    acc[(mh)*4+0][3] = MFMA_(a0_, b3_, acc[(mh)*4+0][3]);               \
    acc[(mh)*4+1][0] = MFMA_(a1_, b0_, acc[(mh)*4+1][0]);               \
    acc[(mh)*4+1][1] = MFMA_(a1_, b1_, acc[(mh)*4+1][1]);               \
    acc[(mh)*4+1][2] = MFMA_(a1_, b2_, acc[(mh)*4+1][2]);               \
    acc[(mh)*4+1][3] = MFMA_(a1_, b3_, acc[(mh)*4+1][3]);               \
    acc[(mh)*4+2][0] = MFMA_(a2_, b0_, acc[(mh)*4+2][0]);               \
    acc[(mh)*4+2][1] = MFMA_(a2_, b1_, acc[(mh)*4+2][1]);               \
    acc[(mh)*4+2][2] = MFMA_(a2_, b2_, acc[(mh)*4+2][2]);               \
    acc[(mh)*4+2][3] = MFMA_(a2_, b3_, acc[(mh)*4+2][3]);               \
    acc[(mh)*4+3][0] = MFMA_(a3_, b0_, acc[(mh)*4+3][0]);               \
    acc[(mh)*4+3][1] = MFMA_(a3_, b1_, acc[(mh)*4+3][1]);               \
    acc[(mh)*4+3][2] = MFMA_(a3_, b2_, acc[(mh)*4+3][2]);               \
    acc[(mh)*4+3][3] = MFMA_(a3_, b3_, acc[(mh)*4+3][3]);               \
    __builtin_amdgcn_s_setprio(0);                                      \
    __builtin_amdgcn_s_barrier();

template <int MODE>
__global__ __launch_bounds__(512, 2) void gemm8(
    const bf16* __restrict__ A, const bf16* __restrict__ B, void* __restrict__ Cv,
    const float* __restrict__ bias, const float* __restrict__ bias_b,
    const float* __restrict__ bias_v, unsigned short* __restrict__ VtOut,
    float* __restrict__ rowsum,
    int M, int N, int K, int lda, int ldb, int ldc,
    long sA, long sB, long sC, float scale) {
  (void)M; (void)N;
  __shared__ __align__(128) char smem[131072];  // 2 bufs x (A 32K | B 32K)
  const int tid = threadIdx.x;
  const int wave = tid >> 6;
  const int lane = tid & 63;
  const int lrow = lane & 15;
  const int quad = lane >> 4;
  const int xt = blockIdx.x, yt = blockIdx.y, zb = blockIdx.z;
  A += (long)zb * sA;
  B += (long)zb * sB;
  const int row0 = yt * 256;
  const int col0 = xt * 256;
  const int wm = (wave >> 2) * 128;  // 0 or 128
  const int wn = (wave & 3) * 64;
  const int wj = wave * 2048;        // this wave's linear staging chunk (j=0)

  // Pre-swizzled global staging sources. LDS dest byte r (rel. to kh region)
  // must hold linear-layout byte l = r ^ (((r>>7)&7)<<4); decode l ->
  // (row x, 16B granule g): x = (l>>6), g = (l>>4)&3 within a 64B row of the
  // [128 rowpair][2 sub][32 k] kh-region layout.
  const bf16* pA0; const bf16* pA1; const bf16* pB0; const bf16* pB1;
  {
    int r0 = wave * 2048 + lane * 16;
    int l0 = r0 ^ (((r0 >> 7) & 7) << 4);
    int x0 = l0 >> 6;
    int g0 = (l0 >> 4) & 3;
    int r1 = r0 + 1024;
    int l1 = r1 ^ (((r1 >> 7) & 7) << 4);
    int x1 = l1 >> 6;
    int g1 = (l1 >> 4) & 3;
    pA0 = A + (long)(row0 + x0) * lda + g0 * 8;
    pA1 = A + (long)(row0 + x1) * lda + g1 * 8;
    pB0 = B + (long)(col0 + x0) * ldb + g0 * 8;
    pB1 = B + (long)(col0 + x1) * ldb + g1 * 8;
  }

  // Swizzled ds_read byte offsets (within a kh region; B adds region base).
  int offA[8], offB[4];
#pragma unroll
  for (int mh = 0; mh < 2; ++mh)
#pragma unroll
    for (int f = 0; f < 4; ++f) {
      int x = wm + mh * 64 + f * 16 + lrow;
      int rb = ((x >> 1) << 7) + ((x & 1) << 6) + (quad << 4);
      offA[mh * 4 + f] = rb ^ (((x >> 1) & 7) << 4);
    }
#pragma unroll
  for (int n = 0; n < 4; ++n) {
    int y = wn + n * 16 + lrow;
    int rb = ((y >> 1) << 7) + ((y & 1) << 6) + (quad << 4);
    offB[n] = (rb ^ (((y >> 1) & 7) << 4)) + 32768;
  }

  f32x4 acc[8][4] = {};
  const int nt = K >> 6;

  // Prologue: prime 6 half-tiles (12 loads/thread), gate tile0-kh0.
  STAGE_A8(0, 0, 0); STAGE_B8(0, 0, 0);    // Akh0(0), Bkh0(0)
  STAGE_A8(1, 0, 0); STAGE_B8(1, 0, 0);    // Akh1(0), Bkh1(0)
  STAGE_A8(0, 1, 64); STAGE_B8(0, 1, 64);  // Akh0(1), Bkh0(1)
  asm volatile("s_waitcnt vmcnt(8)" ::: "memory");
  __builtin_amdgcn_s_barrier();

  for (int u = 0; u < nt; ++u) {
    const int cur = u & 1;
    const int nxt = cur ^ 1;
    const int ks = u << 6;
    const bool st1 = (u + 1 < nt);
    const bool st2 = (u + 2 < nt);
    {  // phase 0: quadrant (mh0, kh0); stage A-kh1(u+1) -> nxt
      PH_READS(0, 0);
      if (st1) STAGE_A8(1, nxt, ks + 64);
      PH_TAIL(0);
    }
    {  // phase 1: (mh1, kh0); stage B-kh1(u+1) -> nxt; WAIT_A gates kh1 reads
      PH_READS(1, 0);
      if (st1) STAGE_B8(1, nxt, ks + 64);
      if (st1) { asm volatile("s_waitcnt vmcnt(8)" ::: "memory"); }
      else     { asm volatile("s_waitcnt vmcnt(0)" ::: "memory"); }
      PH_TAIL(1);
    }
    {  // phase 2: (mh0, kh1); stage A-kh0(u+2) -> cur (region dead after ph1)
      PH_READS(0, 1);
      if (st2) STAGE_A8(0, cur, ks + 128);
      PH_TAIL(0);
    }
    {  // phase 3: (mh1, kh1); stage B-kh0(u+2) -> cur; WAIT_B gates next kh0
      PH_READS(1, 1);
      if (st2) STAGE_B8(0, cur, ks + 128);
      if (st2)                 { asm volatile("s_waitcnt vmcnt(8)" ::: "memory"); }
      else if (u == nt - 2)    { asm volatile("s_waitcnt vmcnt(4)" ::: "memory"); }
      PH_TAIL(1);
    }
  }

  // Epilogue. D mapping (verified): row = quad*4 + r, col = lrow per 16x16.
  if constexpr (MODE == 8) {
    float* C = (float*)Cv + (long)zb * sC;
    const float* rs = rowsum + (long)zb * S_;
#pragma unroll
    for (int m = 0; m < 8; ++m) {
#pragma unroll
      for (int r = 0; r < 4; ++r) {
        const int row = row0 + wm + m * 16 + quad * 4 + r;
        const float inv = 1.0f / rs[row];
#pragma unroll
        for (int n = 0; n < 4; ++n) {
          const int col = col0 + wn + n * 16 + lrow;
          C[(long)row * ldc + col] = acc[m][n][r] * inv;
        }
      }
    }
  } else if constexpr (MODE == 7) {
    unsigned short* C = (unsigned short*)Cv + (long)zb * sC;
    float* rs = rowsum + (long)zb * S_;
    float rsump[8][4];
#pragma unroll
    for (int m = 0; m < 8; ++m)
#pragma unroll
      for (int r = 0; r < 4; ++r) rsump[m][r] = 0.f;
#pragma unroll
    for (int n = 0; n < 4; ++n) {
      const int col = col0 + wn + n * 16 + lrow;
#pragma unroll
      for (int m = 0; m < 8; ++m) {
#pragma unroll
        for (int r = 0; r < 4; ++r) {
          const int row = row0 + wm + m * 16 + quad * 4 + r;
          const float e = __expf(acc[m][n][r] * scale);
          rsump[m][r] += e;
          C[(long)row * ldc + col] = f2bf(e);
        }
      }
    }
#pragma unroll
    for (int m = 0; m < 8; ++m) {
#pragma unroll
      for (int r = 0; r < 4; ++r) {
        float v = rsump[m][r];
        v += __shfl_xor(v, 1);
        v += __shfl_xor(v, 2);
        v += __shfl_xor(v, 4);
        v += __shfl_xor(v, 8);
        if (lrow == 0)
          atomicAdd(&rs[row0 + wm + m * 16 + quad * 4 + r], v);
      }
    }
  } else {  // MODE 6: fused QKV
    if (col0 < 2048) {
      unsigned short* C = (unsigned short*)Cv;
#pragma unroll
      for (int n = 0; n < 4; ++n) {
        const int col = col0 + wn + n * 16 + lrow;
        const float bcol = (col < E_) ? bias[col] : bias_b[col - E_];
#pragma unroll
        for (int m = 0; m < 8; ++m) {
#pragma unroll
          for (int r = 0; r < 4; ++r) {
            const int row = row0 + wm + m * 16 + quad * 4 + r;
            C[(long)row * ldc + col] = f2bf(acc[m][n][r] + bcol);
          }
        }
      }
    } else {
      // V block: write transposed. e = col-2048; Vt[e][bs], 4 contiguous bs.
#pragma unroll
      for (int n = 0; n < 4; ++n) {
        const int e = col0 + wn + n * 16 + lrow - 2048;
        const float bv_ = bias_v[e];
#pragma unroll
        for (int m = 0; m < 8; ++m) {
          const int row = row0 + wm + m * 16 + quad * 4;
          ushort4v o;
          o.x = f2bf(acc[m][n][0] + bv_);
          o.y = f2bf(acc[m][n][1] + bv_);
          o.z = f2bf(acc[m][n][2] + bv_);
          o.w = f2bf(acc[m][n][3] + bv_);
          *(ushort4v*)(VtOut + (long)e * (B_ * S_) + row) = o;
        }
      }
    }
  }
}

// ---------------------------------------------------------------------------
// Old proven 128x128 kernel (kept for PV this round: 256^2 PV grid would be
// only 128 blocks -> half the GPU idle; PV port needs its own tile shape).
// ---------------------------------------------------------------------------
template <int MODE, int SWZ, int NXT>
__global__ __launch_bounds__(256, 4) void gemm_bt(
    const bf16* __restrict__ A, const bf16* __restrict__ B, void* __restrict__ Cv,
    const float* __restrict__ bias, const float* __restrict__ bias_b,
    const float* __restrict__ bias_v, unsigned short* __restrict__ VtOut,
    float* __restrict__ rowsum,
    int M, int N, int K, int lda, int ldb, int ldc,
    long sA, long sB, long sC, float scale, int nyt) {
  __shared__ bf16 As[128 * 64];
  __shared__ bf16 Bs[128 * 64];

  int xt, yt, zb;
  if (SWZ == 0) {
    xt = blockIdx.x; yt = blockIdx.y; zb = blockIdx.z;
  } else {  // SWZ == 1
    const int flat = blockIdx.x;
    const int xcd = flat & 7;
    const int local = flat >> 3;
    zb = xcd >> 1;
    const int w = (xcd & 1) * (NXT * nyt / 2) + local;
    xt = w % NXT; yt = w / NXT;
  }

  A += (long)zb * sA;
  B += (long)zb * sB;
  const int tid = threadIdx.x;
  const int wave = tid >> 6;
  const int lane = tid & 63;
  const int lrow = lane & 15;
  const int quad = lane >> 4;
  const int row0 = yt * 128;
  const int col0 = xt * 128;
  const int wm = (wave >> 1) * 64;
  const int wn = (wave & 1) * 64;

  f32x4 acc[4][4] = {};

  const int r0 = wave * 8 + (lane >> 3);
  const int c0 = (lane & 7) * 8;

  const bf16* pA0 = A + (long)(row0 + r0) * lda + c0;
  const bf16* pA1 = pA0 + 32L * lda;
  const bf16* pA2 = pA0 + 64L * lda;
  const bf16* pA3 = pA0 + 96L * lda;
  const bf16* pB0 = B + (long)(col0 + r0) * ldb + c0;
  const bf16* pB1 = pB0 + 32L * ldb;
  const bf16* pB2 = pB0 + 64L * ldb;
  const bf16* pB3 = pB0 + 96L * ldb;
  bf16* ldsA = As + wave * 512;
  bf16* ldsB = Bs + wave * 512;

  for (int ks = 0; ks < K; ks += 64) {
    load16_to_lds(pA0, ldsA);
    load16_to_lds(pA1, ldsA + 2048);
    load16_to_lds(pA2, ldsA + 4096);
    load16_to_lds(pA3, ldsA + 6144);
    load16_to_lds(pB0, ldsB);
    load16_to_lds(pB1, ldsB + 2048);
    load16_to_lds(pB2, ldsB + 4096);
    load16_to_lds(pB3, ldsB + 6144);
    __syncthreads();
#pragma unroll
    for (int kk = 0; kk < 64; kk += 32) {
      bf16x8 af[4], bfr[4];
#pragma unroll
      for (int i = 0; i < 4; ++i)
        af[i] = *(const bf16x8*)(As + (wm + i * 16 + lrow) * 64 + kk + quad * 8);
#pragma unroll
      for (int j = 0; j < 4; ++j)
        bfr[j] = *(const bf16x8*)(Bs + (wn + j * 16 + lrow) * 64 + kk + quad * 8);
#pragma unroll
      for (int i = 0; i < 4; ++i)
#pragma unroll
        for (int j = 0; j < 4; ++j)
          acc[i][j] = __builtin_amdgcn_mfma_f32_16x16x32_bf16(af[i], bfr[j], acc[i][j], 0, 0, 0);
    }
    __syncthreads();
    pA0 += 64; pA1 += 64; pA2 += 64; pA3 += 64;
    pB0 += 64; pB1 += 64; pB2 += 64; pB3 += 64;
  }

  if (MODE == 8) {
    float* C = (float*)Cv + (long)zb * sC;
    const float* rs = rowsum + (long)zb * S_;
#pragma unroll
    for (int i = 0; i < 4; ++i) {
#pragma unroll
      for (int r = 0; r < 4; ++r) {
        const int row = row0 + wm + i * 16 + quad * 4 + r;
        const float inv = 1.0f / rs[row];
#pragma unroll
        for (int j = 0; j < 4; ++j) {
          const int col = col0 + wn + j * 16 + lrow;
          C[(long)row * ldc + col] = acc[i][j][r] * inv;
        }
      }
    }
  } else if (MODE == 7) {
    unsigned short* C = (unsigned short*)Cv + (long)zb * sC;
    float* rs = rowsum + (long)zb * S_;
    float rsump[4][4];
#pragma unroll
    for (int i = 0; i < 4; ++i)
#pragma unroll
      for (int r = 0; r < 4; ++r) rsump[i][r] = 0.f;
#pragma unroll
    for (int j = 0; j < 4; ++j) {
      const int col = col0 + wn + j * 16 + lrow;
#pragma unroll
      for (int i = 0; i < 4; ++i) {
#pragma unroll
        for (int r = 0; r < 4; ++r) {
          const int row = row0 + wm + i * 16 + quad * 4 + r;
          const float e = __expf(acc[i][j][r] * scale);
          rsump[i][r] += e;
          C[(long)row * ldc + col] = f2bf(e);
        }
      }
    }
#pragma unroll
    for (int i = 0; i < 4; ++i) {
#pragma unroll
      for (int r = 0; r < 4; ++r) {
        float v = rsump[i][r];
        v += __shfl_xor(v, 1);
        v += __shfl_xor(v, 2);
        v += __shfl_xor(v, 4);
        v += __shfl_xor(v, 8);
        if (lrow == 0)
          atomicAdd(&rs[row0 + wm + i * 16 + quad * 4 + r], v);
      }
    }
  } else {  // MODE 6
    if (col0 < 2048) {
      unsigned short* C = (unsigned short*)Cv;
#pragma unroll
      for (int j = 0; j < 4; ++j) {
        const int col = col0 + wn + j * 16 + lrow;
        const float bcol = (col < E_) ? bias[col] : bias_b[col - E_];
#pragma unroll
        for (int i = 0; i < 4; ++i) {
#pragma unroll
          for (int r = 0; r < 4; ++r) {
            const int row = row0 + wm + i * 16 + quad * 4 + r;
            C[(long)row * ldc + col] = f2bf(acc[i][j][r] + bcol);
          }
        }
      }
    } else {
#pragma unroll
      for (int j = 0; j < 4; ++j) {
        const int e = col0 + wn + j * 16 + lrow - 2048;
        const float bv_ = bias_v[e];
#pragma unroll
        for (int i = 0; i < 4; ++i) {
          const int row = row0 + wm + i * 16 + quad * 4;
          ushort4v o;
          o.x = f2bf(acc[i][j][0] + bv_);
          o.y = f2bf(acc[i][j][1] + bv_);
          o.z = f2bf(acc[i][j][2] + bv_);
          o.w = f2bf(acc[i][j][3] + bv_);
          *(ushort4v*)(VtOut + (long)e * (B_ * S_) + row) = o;
        }
      }
    }
  }
}

// ---------------------------------------------------------------------------
extern "C" void kernel_launch(void* const* d_in, const int* in_sizes, int n_in,
                              void* d_out, int out_size, void* d_ws, size_t ws_size,
                              hipStream_t stream) {
  const float* x    = (const float*)d_in[0];
  const float* wq_w = (const float*)d_in[1];
  const float* wq_b = (const float*)d_in[2];
  const float* wk_w = (const float*)d_in[3];
  const float* wk_b = (const float*)d_in[4];
  const float* wv_w = (const float*)d_in[5];
  const float* wv_b = (const float*)d_in[6];
  float* out = (float*)d_out;

  const long NX = (long)B_ * S_ * E_;  // 8388608
  const long NW = (long)E_ * E_;       // 1048576
  char* ws = (char*)d_ws;
  bf16* xb  = (bf16*)ws; ws += NX * 2;
  bf16* wqb = (bf16*)ws; ws += NW * 2;   // xb,wqb,wkb,wvb contiguous
  bf16* wkb = (bf16*)ws; ws += NW * 2;
  bf16* wvb = (bf16*)ws; ws += NW * 2;
  bf16* QK  = (bf16*)ws; ws += 2 * NX * 2;   // [8192 x 2048]: Q | K
  bf16* Vt  = (bf16*)ws; ws += NX * 2;       // [1024 x 8192] (V transposed)
  bf16* Sc  = (bf16*)ws; ws += (long)B_ * S_ * S_ * 2;   // exp-scores
  float* rowsum = (float*)ws; ws += (long)B_ * S_ * 4;   // fp32 row sums

  cvt_all<<<dim3(11264), 256, 0, stream>>>(
      x, wq_w, wk_w, wv_w, (unsigned short*)xb);
  hipMemsetAsync(rowsum, 0, (size_t)B_ * S_ * 4, stream);

  // QKV = x @ [Wq;Wk;Wv]^T + bias  [8192 x 3072], 256^2 8-phase kernel.
  gemm8<6><<<dim3(12, 32, 1), dim3(512), 0, stream>>>(
      xb, wqb, QK, wq_b, wk_b, wv_b, (unsigned short*)Vt, nullptr,
      B_ * S_, 3 * E_, E_, E_, E_, 2 * E_, 0, 0, 0, 1.f);
  // exp-scores = exp(Q @ K^T / 32) + atomic row sums, per batch (z).
  gemm8<7><<<dim3(8, 8, 4), dim3(512), 0, stream>>>(
      QK, QK + E_, Sc, nullptr, nullptr, nullptr, nullptr, rowsum,
      S_, S_, E_, 2 * E_, 2 * E_, S_,
      (long)S_ * 2 * E_, (long)S_ * 2 * E_, (long)S_ * S_, 0.03125f);
  // out = (P~ @ V) / rowsum, per batch, fp32 out (old proven kernel).
  dim3 blk(256);
  gemm_bt<8, 1, 8><<<dim3(512, 1, 1), blk, 0, stream>>>(
      Sc, Vt, out, nullptr, nullptr, nullptr, nullptr, rowsum,
      S_, E_, S_, S_, B_ * S_, E_,
      (long)S_ * S_, (long)S_, (long)S_ * E_, 1.f, 16);
}

// Round 2
// 270.482 us; speedup vs baseline: 1.0162x; 1.0162x over previous
//
#include <hip/hip_runtime.h>
#include <hip/hip_bf16.h>
#include <stdint.h>

#define B_ 4
#define S_ 2048
#define E_ 1024

typedef __bf16 bf16;
typedef __attribute__((ext_vector_type(8))) __bf16 bf16x8;
typedef __attribute__((ext_vector_type(4))) float f32x4;
typedef __attribute__((ext_vector_type(4))) float float4v;
typedef __attribute__((ext_vector_type(4))) unsigned int uint4v;
typedef __attribute__((ext_vector_type(4))) unsigned short ushort4v;

__device__ inline unsigned short f2bf(float f) {
  union { float f; unsigned int u; } c; c.f = f;
  unsigned int u = c.u;
  unsigned int r = (u + 0x7FFFu + ((u >> 16) & 1u)) >> 16;
  return (unsigned short)r;
}

__device__ inline void load16_to_lds(const void* g, void* l) {
  __builtin_amdgcn_global_load_lds(
      (const __attribute__((address_space(1))) void*)g,
      (__attribute__((address_space(3))) void*)l,
      16, 0, 0);
}

// ---------------------------------------------------------------------------
// Merged fp32->bf16 converter: x (8192 blocks) + 3 weights (1024 each).
// ---------------------------------------------------------------------------
__global__ __launch_bounds__(256) void cvt_all(
    const float* __restrict__ x, const float* __restrict__ w0,
    const float* __restrict__ w1, const float* __restrict__ w2,
    unsigned short* __restrict__ out) {
  const long off = (long)blockIdx.x * 256 + threadIdx.x;  // float4 units
  const float* in;
  long ibase;
  if (blockIdx.x < 8192)       { in = x;  ibase = 0; }
  else if (blockIdx.x < 9216)  { in = w0; ibase = 8192L * 256; }
  else if (blockIdx.x < 10240) { in = w1; ibase = 9216L * 256; }
  else                         { in = w2; ibase = 10240L * 256; }
  float4v f = ((const float4v*)in)[off - ibase];
  ushort4v o;
  o.x = f2bf(f.x); o.y = f2bf(f.y); o.z = f2bf(f.z); o.w = f2bf(f.w);
  ((ushort4v*)out)[off] = o;
}

// ---------------------------------------------------------------------------
// gemm8 (R2 rewrite): faithful m201-template port.
// 256x256 tile, BK=64, 8 waves (2M x 4N), per-wave C = 128x64.
// Phase = one 64x32 C-quadrant x full K=64 (16 MFMA). Quadrant order per tile:
// (0,0),(0,1),(1,1),(1,0) with A/B fragments retained in regs (reads 12/4/8/0).
// LDS: 2 dbuf x (A 2x16K row-halves | B 2x16K row-halves) = 128 KiB.
// Row-half = 128 rows x 128B (full BK), staged by 2 global_load_lds/thread.
// Swizzle: granule g' = g ^ (row&7) (involution; 16B granules in 128B rows);
// pre-swizzled global source (full 128B/row coverage) + swizzled ds_read.
// Gates: vmcnt(2) after ph4, vmcnt(4) after ph8; in-flight max 12 loads.
// Raw asm s_barrier (no compiler waitcnt attach); T5 setprio around MFMA.
// MODE 6: fused QKV epilogue; MODE 7: exp-scores + rowsums; MODE 8: PV.
// ---------------------------------------------------------------------------

#define MFMA_(a, b, c) __builtin_amdgcn_mfma_f32_16x16x32_bf16(a, b, c, 0, 0, 0)

#define BAR   asm volatile("s_barrier" ::: "memory")
#define LGKM0 asm volatile("s_waitcnt lgkmcnt(0)" ::: "memory")
#define LGKM8 asm volatile("s_waitcnt lgkmcnt(8)" ::: "memory")
#define VM(n) asm volatile("s_waitcnt vmcnt(" #n ")" ::: "memory")

#define STG_A(H, BUF, tile)                                              \
  { const bf16* s_ = pAs + (long)(H) * 128 * lda + (long)(tile) * 64;    \
    char* d_ = sw + (BUF) * 65536 + (H) * 16384;                         \
    load16_to_lds(s_, d_);                                               \
    load16_to_lds(s_ + a64, d_ + 8192); }

#define STG_B(H, BUF, tile)                                              \
  { const bf16* s_ = pBs + (long)(H) * 128 * ldb + (long)(tile) * 64;    \
    char* d_ = sw + 32768 + (BUF) * 65536 + (H) * 16384;                 \
    load16_to_lds(s_, d_);                                               \
    load16_to_lds(s_ + b64, d_ + 8192); }

#define READ_A4(g, BUF)                                                  \
  { const char* p_ = smem + (BUF) * 65536;                               \
    af[0][0] = *(const bf16x8*)(p_ + offA[(g) + 0]);                     \
    af[0][1] = *(const bf16x8*)(p_ + (offA[(g) + 0] ^ 64));              \
    af[1][0] = *(const bf16x8*)(p_ + offA[(g) + 1]);                     \
    af[1][1] = *(const bf16x8*)(p_ + (offA[(g) + 1] ^ 64));              \
    af[2][0] = *(const bf16x8*)(p_ + offA[(g) + 2]);                     \
    af[2][1] = *(const bf16x8*)(p_ + (offA[(g) + 2] ^ 64));              \
    af[3][0] = *(const bf16x8*)(p_ + offA[(g) + 3]);                     \
    af[3][1] = *(const bf16x8*)(p_ + (offA[(g) + 3] ^ 64)); }

#define READ_B2(BF, g, BUF)                                              \
  { const char* p_ = smem + (BUF) * 65536;                               \
    BF[0][0] = *(const bf16x8*)(p_ + offB[(g) + 0]);                     \
    BF[0][1] = *(const bf16x8*)(p_ + (offB[(g) + 0] ^ 64));              \
    BF[1][0] = *(const bf16x8*)(p_ + offB[(g) + 1]);                     \
    BF[1][1] = *(const bf16x8*)(p_ + (offB[(g) + 1] ^ 64)); }

#define MM1(m, n, ks, BF) \
  acc[m][n] = MFMA_(af[(m) & 3][ks], BF[(n) & 1][ks], acc[m][n])

#define MFMA_Q(qm, qn, BF)                                               \
  __builtin_amdgcn_s_setprio(1);                                         \
  MM1((qm)*4 + 0, (qn)*2 + 0, 0, BF); MM1((qm)*4 + 0, (qn)*2 + 1, 0, BF);\
  MM1((qm)*4 + 1, (qn)*2 + 0, 0, BF); MM1((qm)*4 + 1, (qn)*2 + 1, 0, BF);\
  MM1((qm)*4 + 2, (qn)*2 + 0, 0, BF); MM1((qm)*4 + 2, (qn)*2 + 1, 0, BF);\
  MM1((qm)*4 + 3, (qn)*2 + 0, 0, BF); MM1((qm)*4 + 3, (qn)*2 + 1, 0, BF);\
  MM1((qm)*4 + 0, (qn)*2 + 0, 1, BF); MM1((qm)*4 + 0, (qn)*2 + 1, 1, BF);\
  MM1((qm)*4 + 1, (qn)*2 + 0, 1, BF); MM1((qm)*4 + 1, (qn)*2 + 1, 1, BF);\
  MM1((qm)*4 + 2, (qn)*2 + 0, 1, BF); MM1((qm)*4 + 2, (qn)*2 + 1, 1, BF);\
  MM1((qm)*4 + 3, (qn)*2 + 0, 1, BF); MM1((qm)*4 + 3, (qn)*2 + 1, 1, BF);\
  __builtin_amdgcn_s_setprio(0);

template <int MODE>
__global__ __launch_bounds__(512, 2) void gemm8(
    const bf16* __restrict__ A, const bf16* __restrict__ B, void* __restrict__ Cv,
    const float* __restrict__ bias, const float* __restrict__ bias_b,
    const float* __restrict__ bias_v, unsigned short* __restrict__ VtOut,
    float* __restrict__ rowsum,
    int M, int N, int K, int lda, int ldb, int ldc,
    long sA, long sB, long sC, float scale) {
  (void)M; (void)N;
  __shared__ __align__(128) char smem[131072];
  const int tid = threadIdx.x;
  const int wave = tid >> 6;
  const int lane = tid & 63;
  const int lrow = lane & 15;
  const int quad = lane >> 4;
  const int xt = blockIdx.x, yt = blockIdx.y, zb = blockIdx.z;
  A += (long)zb * sA;
  B += (long)zb * sB;
  const int row0 = yt * 256;
  const int col0 = xt * 256;
  const int wm = (wave >> 2) * 128;  // 0 or 128
  const int wn = (wave & 3) * 64;

  // Staging geometry: thread t stages row (t>>3) of the half, granule
  // (t&7) ^ ((t>>3)&7) -- pre-swizzled source, linear LDS dest (HW lane*16B).
  // Each wave-instruction covers 8 full 128B global rows.
  const int srow = tid >> 3;
  const int sgsrc = ((tid & 7) ^ ((tid >> 3) & 7)) * 8;  // element offset
  const bf16* pAs = A + (long)(row0 + srow) * lda + sgsrc;
  const bf16* pBs = B + (long)(col0 + srow) * ldb + sgsrc;
  const long a64 = 64L * lda, b64 = 64L * ldb;
  char* const sw = smem + wave * 1024;  // wave-uniform staging base (j=0)

  // ds_read byte offsets (ks=0; ks=1 = ^64). Granule = (ks*4+quad) ^ (row&7);
  // row&7 == lrow&7 for all fragments.
  const int sg = (quad ^ (lrow & 7)) << 4;
  int offA[8], offB[4];
#pragma unroll
  for (int m = 0; m < 8; ++m)
    offA[m] = (wave >> 2) * 16384 + (m * 16 + lrow) * 128 + sg;
#pragma unroll
  for (int n = 0; n < 4; ++n)
    offB[n] = 32768 + ((wave >> 1) & 1) * 16384 +
              ((wave & 1) * 64 + n * 16 + lrow) * 128 + sg;

  f32x4 acc[8][4] = {};
  bf16x8 af[4][2], bfA[2][2], bfB[2][2];
  const int nt = K >> 6;  // 16 for both dispatches (even, >=4)

  // Prologue: tile0 complete + A halves of tile1 (12 loads); steady G1 state.
  STG_A(0, 0, 0); STG_A(1, 0, 0);
  STG_B(0, 0, 0); STG_B(1, 0, 0);
  STG_A(0, 1, 1); STG_A(1, 1, 1);
  VM(4);
  BAR;

  for (int u = 0; u + 3 < nt; u += 2) {
    // ===== tile u (buf0) =====
    // ph1 (q 0,0): 12 reads; stage B0(u+1)
    READ_A4(0, 0); READ_B2(bfA, 0, 0);
    STG_B(0, 1, u + 1);
    LGKM8; BAR; LGKM0;
    MFMA_Q(0, 0, bfA);
    BAR;
    // ph2 (q 0,1): 4 reads; stage B1(u+1)
    READ_B2(bfB, 2, 0);
    STG_B(1, 1, u + 1);
    BAR; LGKM0;
    MFMA_Q(0, 1, bfB);
    BAR;
    // ph3 (q 1,1): 8 reads (A high half)
    READ_A4(4, 0);
    BAR; LGKM0;
    MFMA_Q(1, 1, bfB);
    BAR;
    // ph4 (q 1,0): no reads; stage A0(u+2); gate tile u+1
    STG_A(0, 0, u + 2);
    VM(2);
    BAR;
    MFMA_Q(1, 0, bfA);
    BAR;

    // ===== tile u+1 (buf1) =====
    // ph5 (q 0,0): 12 reads; stage A1(u+2), B0(u+2)
    READ_A4(0, 1); READ_B2(bfA, 0, 1);
    STG_A(1, 0, u + 2); STG_B(0, 0, u + 2);
    LGKM8; BAR; LGKM0;
    MFMA_Q(0, 0, bfA);
    BAR;
    // ph6 (q 0,1): 4 reads; stage B1(u+2)
    READ_B2(bfB, 2, 1);
    STG_B(1, 0, u + 2);
    BAR; LGKM0;
    MFMA_Q(0, 1, bfB);
    BAR;
    // ph7 (q 1,1): 8 reads
    READ_A4(4, 1);
    BAR; LGKM0;
    MFMA_Q(1, 1, bfB);
    BAR;
    // ph8 (q 1,0): stage A0,A1(u+3); gate tile u+2
    STG_A(0, 1, u + 3); STG_A(1, 1, u + 3);
    VM(4);
    BAR;
    MFMA_Q(1, 0, bfA);
    BAR;
  }

  // ===== final iteration: tiles nt-2 (buf0), nt-1 (buf1) =====
  READ_A4(0, 0); READ_B2(bfA, 0, 0);
  STG_B(0, 1, nt - 1);
  LGKM8; BAR; LGKM0;
  MFMA_Q(0, 0, bfA);
  BAR;

  READ_B2(bfB, 2, 0);
  STG_B(1, 1, nt - 1);
  BAR; LGKM0;
  MFMA_Q(0, 1, bfB);
  BAR;

  READ_A4(4, 0);
  BAR; LGKM0;
  MFMA_Q(1, 1, bfB);
  BAR;

  VM(0);
  BAR;
  MFMA_Q(1, 0, bfA);
  BAR;

  READ_A4(0, 1); READ_B2(bfA, 0, 1);
  LGKM8; BAR; LGKM0;
  MFMA_Q(0, 0, bfA);
  BAR;

  READ_B2(bfB, 2, 1);
  BAR; LGKM0;
  MFMA_Q(0, 1, bfB);
  BAR;

  READ_A4(4, 1);
  BAR; LGKM0;
  MFMA_Q(1, 1, bfB);
  BAR;

  MFMA_Q(1, 0, bfA);

  // Epilogue. D mapping (verified): row = quad*4 + r, col = lrow per 16x16.
  if constexpr (MODE == 8) {
    float* C = (float*)Cv + (long)zb * sC;
    const float* rs = rowsum + (long)zb * S_;
#pragma unroll
    for (int m = 0; m < 8; ++m) {
#pragma unroll
      for (int r = 0; r < 4; ++r) {
        const int row = row0 + wm + m * 16 + quad * 4 + r;
        const float inv = 1.0f / rs[row];
#pragma unroll
        for (int n = 0; n < 4; ++n) {
          const int col = col0 + wn + n * 16 + lrow;
          C[(long)row * ldc + col] = acc[m][n][r] * inv;
        }
      }
    }
  } else if constexpr (MODE == 7) {
    unsigned short* C = (unsigned short*)Cv + (long)zb * sC;
    float* rs = rowsum + (long)zb * S_;
    float rsump[8][4];
#pragma unroll
    for (int m = 0; m < 8; ++m)
#pragma unroll
      for (int r = 0; r < 4; ++r) rsump[m][r] = 0.f;
#pragma unroll
    for (int n = 0; n < 4; ++n) {
      const int col = col0 + wn + n * 16 + lrow;
#pragma unroll
      for (int m = 0; m < 8; ++m) {
#pragma unroll
        for (int r = 0; r < 4; ++r) {
          const int row = row0 + wm + m * 16 + quad * 4 + r;
          const float e = __expf(acc[m][n][r] * scale);
          rsump[m][r] += e;
          C[(long)row * ldc + col] = f2bf(e);
        }
      }
    }
#pragma unroll
    for (int m = 0; m < 8; ++m) {
#pragma unroll
      for (int r = 0; r < 4; ++r) {
        float v = rsump[m][r];
        v += __shfl_xor(v, 1);
        v += __shfl_xor(v, 2);
        v += __shfl_xor(v, 4);
        v += __shfl_xor(v, 8);
        if (lrow == 0)
          atomicAdd(&rs[row0 + wm + m * 16 + quad * 4 + r], v);
      }
    }
  } else {  // MODE 6: fused QKV
    if (col0 < 2048) {
      unsigned short* C = (unsigned short*)Cv;
#pragma unroll
      for (int n = 0; n < 4; ++n) {
        const int col = col0 + wn + n * 16 + lrow;
        const float bcol = (col < E_) ? bias[col] : bias_b[col - E_];
#pragma unroll
        for (int m = 0; m < 8; ++m) {
#pragma unroll
          for (int r = 0; r < 4; ++r) {
            const int row = row0 + wm + m * 16 + quad * 4 + r;
            C[(long)row * ldc + col] = f2bf(acc[m][n][r] + bcol);
          }
        }
      }
    } else {
      // V block: write transposed. e = col-2048; Vt[e][bs], 4 contiguous bs.
#pragma unroll
      for (int n = 0; n < 4; ++n) {
        const int e = col0 + wn + n * 16 + lrow - 2048;
        const float bv_ = bias_v[e];
#pragma unroll
        for (int m = 0; m < 8; ++m) {
          const int row = row0 + wm + m * 16 + quad * 4;
          ushort4v o;
          o.x = f2bf(acc[m][n][0] + bv_);
          o.y = f2bf(acc[m][n][1] + bv_);
          o.z = f2bf(acc[m][n][2] + bv_);
          o.w = f2bf(acc[m][n][3] + bv_);
          *(ushort4v*)(VtOut + (long)e * (B_ * S_) + row) = o;
        }
      }
    }
  }
}

// ---------------------------------------------------------------------------
// Old proven 128x128 kernel (PV only: its grid is 512 blocks; 256^2 PV tile
// would leave half the GPU idle).
// ---------------------------------------------------------------------------
template <int MODE, int SWZ, int NXT>
__global__ __launch_bounds__(256, 4) void gemm_bt(
    const bf16* __restrict__ A, const bf16* __restrict__ B, void* __restrict__ Cv,
    const float* __restrict__ bias, const float* __restrict__ bias_b,
    const float* __restrict__ bias_v, unsigned short* __restrict__ VtOut,
    float* __restrict__ rowsum,
    int M, int N, int K, int lda, int ldb, int ldc,
    long sA, long sB, long sC, float scale, int nyt) {
  __shared__ bf16 As[128 * 64];
  __shared__ bf16 Bs[128 * 64];

  int xt, yt, zb;
  if (SWZ == 0) {
    xt = blockIdx.x; yt = blockIdx.y; zb = blockIdx.z;
  } else {  // SWZ == 1
    const int flat = blockIdx.x;
    const int xcd = flat & 7;
    const int local = flat >> 3;
    zb = xcd >> 1;
    const int w = (xcd & 1) * (NXT * nyt / 2) + local;
    xt = w % NXT; yt = w / NXT;
  }

  A += (long)zb * sA;
  B += (long)zb * sB;
  const int tid = threadIdx.x;
  const int wave = tid >> 6;
  const int lane = tid & 63;
  const int lrow = lane & 15;
  const int quad = lane >> 4;
  const int row0 = yt * 128;
  const int col0 = xt * 128;
  const int wm = (wave >> 1) * 64;
  const int wn = (wave & 1) * 64;

  f32x4 acc[4][4] = {};

  const int r0 = wave * 8 + (lane >> 3);
  const int c0 = (lane & 7) * 8;

  const bf16* pA0 = A + (long)(row0 + r0) * lda + c0;
  const bf16* pA1 = pA0 + 32L * lda;
  const bf16* pA2 = pA0 + 64L * lda;
  const bf16* pA3 = pA0 + 96L * lda;
  const bf16* pB0 = B + (long)(col0 + r0) * ldb + c0;
  const bf16* pB1 = pB0 + 32L * ldb;
  const bf16* pB2 = pB0 + 64L * ldb;
  const bf16* pB3 = pB0 + 96L * ldb;
  bf16* ldsA = As + wave * 512;
  bf16* ldsB = Bs + wave * 512;

  for (int ks = 0; ks < K; ks += 64) {
    load16_to_lds(pA0, ldsA);
    load16_to_lds(pA1, ldsA + 2048);
    load16_to_lds(pA2, ldsA + 4096);
    load16_to_lds(pA3, ldsA + 6144);
    load16_to_lds(pB0, ldsB);
    load16_to_lds(pB1, ldsB + 2048);
    load16_to_lds(pB2, ldsB + 4096);
    load16_to_lds(pB3, ldsB + 6144);
    __syncthreads();
#pragma unroll
    for (int kk = 0; kk < 64; kk += 32) {
      bf16x8 af[4], bfr[4];
#pragma unroll
      for (int i = 0; i < 4; ++i)
        af[i] = *(const bf16x8*)(As + (wm + i * 16 + lrow) * 64 + kk + quad * 8);
#pragma unroll
      for (int j = 0; j < 4; ++j)
        bfr[j] = *(const bf16x8*)(Bs + (wn + j * 16 + lrow) * 64 + kk + quad * 8);
#pragma unroll
      for (int i = 0; i < 4; ++i)
#pragma unroll
        for (int j = 0; j < 4; ++j)
          acc[i][j] = __builtin_amdgcn_mfma_f32_16x16x32_bf16(af[i], bfr[j], acc[i][j], 0, 0, 0);
    }
    __syncthreads();
    pA0 += 64; pA1 += 64; pA2 += 64; pA3 += 64;
    pB0 += 64; pB1 += 64; pB2 += 64; pB3 += 64;
  }

  if (MODE == 8) {
    float* C = (float*)Cv + (long)zb * sC;
    const float* rs = rowsum + (long)zb * S_;
#pragma unroll
    for (int i = 0; i < 4; ++i) {
#pragma unroll
      for (int r = 0; r < 4; ++r) {
        const int row = row0 + wm + i * 16 + quad * 4 + r;
        const float inv = 1.0f / rs[row];
#pragma unroll
        for (int j = 0; j < 4; ++j) {
          const int col = col0 + wn + j * 16 + lrow;
          C[(long)row * ldc + col] = acc[i][j][r] * inv;
        }
      }
    }
  } else if (MODE == 7) {
    unsigned short* C = (unsigned short*)Cv + (long)zb * sC;
    float* rs = rowsum + (long)zb * S_;
    float rsump[4][4];
#pragma unroll
    for (int i = 0; i < 4; ++i)
#pragma unroll
      for (int r = 0; r < 4; ++r) rsump[i][r] = 0.f;
#pragma unroll
    for (int j = 0; j < 4; ++j) {
      const int col = col0 + wn + j * 16 + lrow;
#pragma unroll
      for (int i = 0; i < 4; ++i) {
#pragma unroll
        for (int r = 0; r < 4; ++r) {
          const int row = row0 + wm + i * 16 + quad * 4 + r;
          const float e = __expf(acc[i][j][r] * scale);
          rsump[i][r] += e;
          C[(long)row * ldc + col] = f2bf(e);
        }
      }
    }
#pragma unroll
    for (int i = 0; i < 4; ++i) {
#pragma unroll
      for (int r = 0; r < 4; ++r) {
        float v = rsump[i][r];
        v += __shfl_xor(v, 1);
        v += __shfl_xor(v, 2);
        v += __shfl_xor(v, 4);
        v += __shfl_xor(v, 8);
        if (lrow == 0)
          atomicAdd(&rs[row0 + wm + i * 16 + quad * 4 + r], v);
      }
    }
  } else {  // MODE 6
    if (col0 < 2048) {
      unsigned short* C = (unsigned short*)Cv;
#pragma unroll
      for (int j = 0; j < 4; ++j) {
        const int col = col0 + wn + j * 16 + lrow;
        const float bcol = (col < E_) ? bias[col] : bias_b[col - E_];
#pragma unroll
        for (int i = 0; i < 4; ++i) {
#pragma unroll
          for (int r = 0; r < 4; ++r) {
            const int row = row0 + wm + i * 16 + quad * 4 + r;
            C[(long)row * ldc + col] = f2bf(acc[i][j][r] + bcol);
          }
        }
      }
    } else {
#pragma unroll
      for (int j = 0; j < 4; ++j) {
        const int e = col0 + wn + j * 16 + lrow - 2048;
        const float bv_ = bias_v[e];
#pragma unroll
        for (int i = 0; i < 4; ++i) {
          const int row = row0 + wm + i * 16 + quad * 4;
          ushort4v o;
          o.x = f2bf(acc[i][j][0] + bv_);
          o.y = f2bf(acc[i][j][1] + bv_);
          o.z = f2bf(acc[i][j][2] + bv_);
          o.w = f2bf(acc[i][j][3] + bv_);
          *(ushort4v*)(VtOut + (long)e * (B_ * S_) + row) = o;
        }
      }
    }
  }
}

// ---------------------------------------------------------------------------
extern "C" void kernel_launch(void* const* d_in, const int* in_sizes, int n_in,
                              void* d_out, int out_size, void* d_ws, size_t ws_size,
                              hipStream_t stream) {
  const float* x    = (const float*)d_in[0];
  const float* wq_w = (const float*)d_in[1];
  const float* wq_b = (const float*)d_in[2];
  const float* wk_w = (const float*)d_in[3];
  const float* wk_b = (const float*)d_in[4];
  const float* wv_w = (const float*)d_in[5];
  const float* wv_b = (const float*)d_in[6];
  float* out = (float*)d_out;

  const long NX = (long)B_ * S_ * E_;  // 8388608
  const long NW = (long)E_ * E_;       // 1048576
  char* ws = (char*)d_ws;
  bf16* xb  = (bf16*)ws; ws += NX * 2;
  bf16* wqb = (bf16*)ws; ws += NW * 2;   // xb,wqb,wkb,wvb contiguous
  bf16* wkb = (bf16*)ws; ws += NW * 2;
  bf16* wvb = (bf16*)ws; ws += NW * 2;
  bf16* QK  = (bf16*)ws; ws += 2 * NX * 2;   // [8192 x 2048]: Q | K
  bf16* Vt  = (bf16*)ws; ws += NX * 2;       // [1024 x 8192] (V transposed)
  bf16* Sc  = (bf16*)ws; ws += (long)B_ * S_ * S_ * 2;   // exp-scores
  float* rowsum = (float*)ws; ws += (long)B_ * S_ * 4;   // fp32 row sums

  cvt_all<<<dim3(11264), 256, 0, stream>>>(
      x, wq_w, wk_w, wv_w, (unsigned short*)xb);
  hipMemsetAsync(rowsum, 0, (size_t)B_ * S_ * 4, stream);

  // QKV = x @ [Wq;Wk;Wv]^T + bias  [8192 x 3072], 256^2 8-phase kernel.
  gemm8<6><<<dim3(12, 32, 1), dim3(512), 0, stream>>>(
      xb, wqb, QK, wq_b, wk_b, wv_b, (unsigned short*)Vt, nullptr,
      B_ * S_, 3 * E_, E_, E_, E_, 2 * E_, 0, 0, 0, 1.f);
  // exp-scores = exp(Q @ K^T / 32) + atomic row sums, per batch (z).
  gemm8<7><<<dim3(8, 8, 4), dim3(512), 0, stream>>>(
      QK, QK + E_, Sc, nullptr, nullptr, nullptr, nullptr, rowsum,
      S_, S_, E_, 2 * E_, 2 * E_, S_,
      (long)S_ * 2 * E_, (long)S_ * 2 * E_, (long)S_ * S_, 0.03125f);
  // out = (P~ @ V) / rowsum, per batch, fp32 out (old proven kernel).
  dim3 blk(256);
  gemm_bt<8, 1, 8><<<dim3(512, 1, 1), blk, 0, stream>>>(
      Sc, Vt, out, nullptr, nullptr, nullptr, nullptr, rowsum,
      S_, E_, S_, S_, B_ * S_, E_,
      (long)S_ * S_, (long)S_, (long)S_ * E_, 1.f, 16);
}

// Round 3
// 256.530 us; speedup vs baseline: 1.0715x; 1.0544x over previous
//
#include <hip/hip_runtime.h>
#include <hip/hip_bf16.h>
#include <stdint.h>

#define B_ 4
#define S_ 2048
#define E_ 1024

// R1/R2 post-mortem (8-phase 256^2 gemm8 port, both reverted):
//  - T2 swizzle verified: SQ_LDS_BANK_CONFLICT 1.9e7 -> 0, correctness OK.
//  - Both 8-phase schedules (K-half phases R1, m201 quadrant phases R2 with
//    raw s_barrier + counted vmcnt gates) landed at ~80 us, MfmaUtil ~25%
//    vs this kernel's 75 us / 28%. Phase time ~3-6x the overlapped ideal.
//  - Leading theory: hipcc inserts its own s_waitcnt vmcnt(0) before each
//    phase's ds_reads (it tracks global_load_lds as an LDS write), draining
//    just-issued prefetches and exposing full memory latency per phase.
//    Unverifiable without disasm access in this loop -> parked.

typedef __bf16 bf16;
typedef __attribute__((ext_vector_type(8))) __bf16 bf16x8;
typedef __attribute__((ext_vector_type(4))) float f32x4;
typedef __attribute__((ext_vector_type(4))) float float4v;
typedef __attribute__((ext_vector_type(4))) unsigned int uint4v;
typedef __attribute__((ext_vector_type(4))) unsigned short ushort4v;

__device__ inline unsigned short f2bf(float f) {
  union { float f; unsigned int u; } c; c.f = f;
  unsigned int u = c.u;
  unsigned int r = (u + 0x7FFFu + ((u >> 16) & 1u)) >> 16;
  return (unsigned short)r;
}

__device__ inline void load16_to_lds(const void* g, void* l) {
  __builtin_amdgcn_global_load_lds(
      (const __attribute__((address_space(1))) void*)g,
      (__attribute__((address_space(3))) void*)l,
      16, 0, 0);
}

// ---------------------------------------------------------------------------
// Merged fp32->bf16 converter: x (8192 blocks) + 3 weights (1024 each) +
// rowsum zeroing (8 blocks) -- replaces the separate hipMemsetAsync dispatch.
// Outputs contiguous in ws (xb | wqb | wkb | wvb), one flat store index.
// ---------------------------------------------------------------------------
__global__ __launch_bounds__(256) void cvt_all(
    const float* __restrict__ x, const float* __restrict__ w0,
    const float* __restrict__ w1, const float* __restrict__ w2,
    unsigned short* __restrict__ out, float* __restrict__ rowsum) {
  if (blockIdx.x >= 11264) {  // 8 blocks: zero rowsum[8192] (fp32)
    rowsum[(blockIdx.x - 11264) * 256 + threadIdx.x] = 0.f;
    return;
  }
  const long off = (long)blockIdx.x * 256 + threadIdx.x;  // float4 units
  const float* in;
  long ibase;
  if (blockIdx.x < 8192)       { in = x;  ibase = 0; }
  else if (blockIdx.x < 9216)  { in = w0; ibase = 8192L * 256; }
  else if (blockIdx.x < 10240) { in = w1; ibase = 9216L * 256; }
  else                         { in = w2; ibase = 10240L * 256; }
  float4v f = ((const float4v*)in)[off - ibase];
  ushort4v o;
  o.x = f2bf(f.x); o.y = f2bf(f.y); o.z = f2bf(f.z); o.w = f2bf(f.w);
  ((ushort4v*)out)[off] = o;
}

// ---------------------------------------------------------------------------
// bt-GEMM: C[m][n] = sum_k A[m][k] * B[n][k]   [R4/R5-proven K-loop]
// SWZ 0: (x,y,z) = blockIdx            [QKV: R7-measured best, 75 µs]
// SWZ 1: 1D grid; XCD-pinned batches: xcd=id&7 owns batch z=xcd>>1
// MODE 6: fused QKV projection epilogue (QK rows + transposed V)
// MODE 7: scores: write exp(acc*scale) bf16 + atomic fp32 row-sums
// MODE 8: PV: fp32 out, divided by rowsum[row]
// ---------------------------------------------------------------------------
template <int MODE, int SWZ, int NXT>
__global__ __launch_bounds__(256, 4) void gemm_bt(
    const bf16* __restrict__ A, const bf16* __restrict__ B, void* __restrict__ Cv,
    const float* __restrict__ bias, const float* __restrict__ bias_b,
    const float* __restrict__ bias_v, unsigned short* __restrict__ VtOut,
    float* __restrict__ rowsum,
    int M, int N, int K, int lda, int ldb, int ldc,
    long sA, long sB, long sC, float scale, int nyt) {
  __shared__ bf16 As[128 * 64];
  __shared__ bf16 Bs[128 * 64];

  int xt, yt, zb;
  if (SWZ == 0) {
    xt = blockIdx.x; yt = blockIdx.y; zb = blockIdx.z;
  } else {  // SWZ == 1
    const int flat = blockIdx.x;
    const int xcd = flat & 7;
    const int local = flat >> 3;            // 0 .. NXT*nyt/2 - 1
    zb = xcd >> 1;
    const int w = (xcd & 1) * (NXT * nyt / 2) + local;
    xt = w % NXT; yt = w / NXT;
  }

  A += (long)zb * sA;
  B += (long)zb * sB;
  const int tid = threadIdx.x;
  const int wave = tid >> 6;
  const int lane = tid & 63;
  const int lrow = lane & 15;
  const int quad = lane >> 4;
  const int row0 = yt * 128;
  const int col0 = xt * 128;
  const int wm = (wave >> 1) * 64;
  const int wn = (wave & 1) * 64;

  f32x4 acc[4][4] = {};

  // staging geometry: r0 in [0,32), c0 in {0,8,...,56}; rows r0+32i
  const int r0 = wave * 8 + (lane >> 3);
  const int c0 = (lane & 7) * 8;

  const bf16* pA0 = A + (long)(row0 + r0) * lda + c0;
  const bf16* pA1 = pA0 + 32L * lda;
  const bf16* pA2 = pA0 + 64L * lda;
  const bf16* pA3 = pA0 + 96L * lda;
  const bf16* pB0 = B + (long)(col0 + r0) * ldb + c0;
  const bf16* pB1 = pB0 + 32L * ldb;
  const bf16* pB2 = pB0 + 64L * ldb;
  const bf16* pB3 = pB0 + 96L * ldb;
  bf16* ldsA = As + wave * 512;  // wave-uniform; HW scatters lane*16B
  bf16* ldsB = Bs + wave * 512;

  for (int ks = 0; ks < K; ks += 64) {
    load16_to_lds(pA0, ldsA);
    load16_to_lds(pA1, ldsA + 2048);
    load16_to_lds(pA2, ldsA + 4096);
    load16_to_lds(pA3, ldsA + 6144);
    load16_to_lds(pB0, ldsB);
    load16_to_lds(pB1, ldsB + 2048);
    load16_to_lds(pB2, ldsB + 4096);
    load16_to_lds(pB3, ldsB + 6144);
    __syncthreads();
#pragma unroll
    for (int kk = 0; kk < 64; kk += 32) {
      bf16x8 af[4], bfr[4];
#pragma unroll
      for (int i = 0; i < 4; ++i)
        af[i] = *(const bf16x8*)(As + (wm + i * 16 + lrow) * 64 + kk + quad * 8);
#pragma unroll
      for (int j = 0; j < 4; ++j)
        bfr[j] = *(const bf16x8*)(Bs + (wn + j * 16 + lrow) * 64 + kk + quad * 8);
#pragma unroll
      for (int i = 0; i < 4; ++i)
#pragma unroll
        for (int j = 0; j < 4; ++j)
          acc[i][j] = __builtin_amdgcn_mfma_f32_16x16x32_bf16(af[i], bfr[j], acc[i][j], 0, 0, 0);
    }
    __syncthreads();
    pA0 += 64; pA1 += 64; pA2 += 64; pA3 += 64;
    pB0 += 64; pB1 += 64; pB2 += 64; pB3 += 64;
  }

  // epilogue: D mapping (verified m89/m91): row = quad*4 + r (m), col = lrow (n)
  if (MODE == 8) {
    // PV: fp32 out, scaled by 1/rowsum[row] (rowsum L2-hot, 32 KB)
    float* C = (float*)Cv + (long)zb * sC;
    const float* rs = rowsum + (long)zb * S_;
#pragma unroll
    for (int i = 0; i < 4; ++i) {
#pragma unroll
      for (int r = 0; r < 4; ++r) {
        const int row = row0 + wm + i * 16 + quad * 4 + r;
        const float inv = 1.0f / rs[row];
#pragma unroll
        for (int j = 0; j < 4; ++j) {
          const int col = col0 + wn + j * 16 + lrow;
          C[(long)row * ldc + col] = acc[i][j][r] * inv;
        }
      }
    }
  } else if (MODE == 7) {
    // scores: P~ = exp(s*scale) (no max subtraction: |s| <~ 6), bf16 store,
    // fp32 row-sums via shuffle-reduce over lrow + one atomicAdd per row/wave.
    unsigned short* C = (unsigned short*)Cv + (long)zb * sC;
    float* rs = rowsum + (long)zb * S_;
    float rsump[4][4];
#pragma unroll
    for (int i = 0; i < 4; ++i)
#pragma unroll
      for (int r = 0; r < 4; ++r) rsump[i][r] = 0.f;
#pragma unroll
    for (int j = 0; j < 4; ++j) {
      const int col = col0 + wn + j * 16 + lrow;
#pragma unroll
      for (int i = 0; i < 4; ++i) {
#pragma unroll
        for (int r = 0; r < 4; ++r) {
          const int row = row0 + wm + i * 16 + quad * 4 + r;
          const float e = __expf(acc[i][j][r] * scale);
          rsump[i][r] += e;
          C[(long)row * ldc + col] = f2bf(e);
        }
      }
    }
#pragma unroll
    for (int i = 0; i < 4; ++i) {
#pragma unroll
      for (int r = 0; r < 4; ++r) {
        float v = rsump[i][r];
        v += __shfl_xor(v, 1);
        v += __shfl_xor(v, 2);
        v += __shfl_xor(v, 4);
        v += __shfl_xor(v, 8);
        if (lrow == 0)
          atomicAdd(&rs[row0 + wm + i * 16 + quad * 4 + r], v);
      }
    }
  } else {  // MODE 6: fused QKV
    if (col0 < 2048) {
      unsigned short* C = (unsigned short*)Cv;
#pragma unroll
      for (int j = 0; j < 4; ++j) {
        const int col = col0 + wn + j * 16 + lrow;
        const float bcol = (col < E_) ? bias[col] : bias_b[col - E_];
#pragma unroll
        for (int i = 0; i < 4; ++i) {
#pragma unroll
          for (int r = 0; r < 4; ++r) {
            const int row = row0 + wm + i * 16 + quad * 4 + r;
            C[(long)row * ldc + col] = f2bf(acc[i][j][r] + bcol);
          }
        }
      }
    } else {
      // V block: write transposed. e = col-2048; Vt[e][bs], bs-run of 4 contiguous.
#pragma unroll
      for (int j = 0; j < 4; ++j) {
        const int e = col0 + wn + j * 16 + lrow - 2048;
        const float bv_ = bias_v[e];
#pragma unroll
        for (int i = 0; i < 4; ++i) {
          const int row = row0 + wm + i * 16 + quad * 4;  // base of 4 consecutive bs
          ushort4v o;
          o.x = f2bf(acc[i][j][0] + bv_);
          o.y = f2bf(acc[i][j][1] + bv_);
          o.z = f2bf(acc[i][j][2] + bv_);
          o.w = f2bf(acc[i][j][3] + bv_);
          *(ushort4v*)(VtOut + (long)e * (B_ * S_) + row) = o;
        }
      }
    }
  }
}

// ---------------------------------------------------------------------------
extern "C" void kernel_launch(void* const* d_in, const int* in_sizes, int n_in,
                              void* d_out, int out_size, void* d_ws, size_t ws_size,
                              hipStream_t stream) {
  const float* x    = (const float*)d_in[0];
  const float* wq_w = (const float*)d_in[1];
  const float* wq_b = (const float*)d_in[2];
  const float* wk_w = (const float*)d_in[3];
  const float* wk_b = (const float*)d_in[4];
  const float* wv_w = (const float*)d_in[5];
  const float* wv_b = (const float*)d_in[6];
  float* out = (float*)d_out;

  const long NX = (long)B_ * S_ * E_;  // 8388608
  const long NW = (long)E_ * E_;       // 1048576
  char* ws = (char*)d_ws;
  bf16* xb  = (bf16*)ws; ws += NX * 2;
  bf16* wqb = (bf16*)ws; ws += NW * 2;   // xb,wqb,wkb,wvb contiguous (cvt_all writes all four)
  bf16* wkb = (bf16*)ws; ws += NW * 2;
  bf16* wvb = (bf16*)ws; ws += NW * 2;
  bf16* QK  = (bf16*)ws; ws += 2 * NX * 2;   // [8192 x 2048]: cols 0..1023 = Q, 1024..2047 = K
  bf16* Vt  = (bf16*)ws; ws += NX * 2;       // [1024 x 8192] (V transposed)
  bf16* Sc  = (bf16*)ws; ws += (long)B_ * S_ * S_ * 2;   // exp-scores
  float* rowsum = (float*)ws; ws += (long)B_ * S_ * 4;   // fp32 row sums

  // single merged convert dispatch (x + 3 weights + rowsum zeroing)
  cvt_all<<<dim3(11272), 256, 0, stream>>>(
      x, wq_w, wk_w, wv_w, (unsigned short*)xb, rowsum);

  dim3 blk(256);
  // QKV = x @ [Wq;Wk;Wv]^T + bias  [8192 x 3072], linear grid (R7-measured 75 µs).
  gemm_bt<6, 0, 24><<<dim3((3 * E_) / 128, (B_ * S_) / 128, 1), blk, 0, stream>>>(
      xb, wqb, QK, wq_b, wk_b, wv_b, (unsigned short*)Vt, nullptr,
      B_ * S_, 3 * E_, E_, E_, E_, 2 * E_, 0, 0, 0, 1.f, 64);
  // exp-scores = exp(Q @ K^T / 32) + atomic row sums. SWZ=1 batch pinning.
  gemm_bt<7, 1, 16><<<dim3(1024, 1, 1), blk, 0, stream>>>(
      QK, QK + E_, Sc, nullptr, nullptr, nullptr, nullptr, rowsum,
      S_, S_, E_, 2 * E_, 2 * E_, S_,
      (long)S_ * 2 * E_, (long)S_ * 2 * E_, (long)S_ * S_, 0.03125f, 16);
  // out = (P~ @ V) / rowsum, per batch, fp32 out. SWZ=1 batch pinning.
  gemm_bt<8, 1, 8><<<dim3(512, 1, 1), blk, 0, stream>>>(
      Sc, Vt, out, nullptr, nullptr, nullptr, nullptr, rowsum,
      S_, E_, S_, S_, B_ * S_, E_,
      (long)S_ * S_, (long)S_, (long)S_ * E_, 1.f, 16);
}